// Round 1
// baseline (294.676 us; speedup 1.0000x reference)
//
#include <hip/hip_runtime.h>

// GainesEdgeDetect, single bit-cycle.
// Algebraic simplification: sel==0 always -> mux picks first operand, so
//   out = FSUAbs_bit(inp_Pr_i_j, cnt_x)
// Only d_in[0] (x) and d_in[4] (cnt_x) are live. Elementwise, memory-bound:
// 192 MiB total traffic -> ~32 us at ~6.3 TB/s achievable HBM BW.

__global__ __launch_bounds__(256) void GainesEdgeDetect_kernel(
    const float4* __restrict__ x4,
    const float4* __restrict__ c4,
    float4* __restrict__ o4,
    int n4)
{
    int i = blockIdx.x * blockDim.x + threadIdx.x;
    if (i >= n4) return;

    float4 x = x4[i];
    float4 c = c4[i];
    float4 o;

    // cn = clip(cnt + 2x - 1, 0, 15); out = (cn < 8) ? (1 - x) : x
    {
        float cn = fminf(fmaxf(fmaf(2.0f, x.x, c.x - 1.0f), 0.0f), 15.0f);
        o.x = (cn < 8.0f) ? (1.0f - x.x) : x.x;
    }
    {
        float cn = fminf(fmaxf(fmaf(2.0f, x.y, c.y - 1.0f), 0.0f), 15.0f);
        o.y = (cn < 8.0f) ? (1.0f - x.y) : x.y;
    }
    {
        float cn = fminf(fmaxf(fmaf(2.0f, x.z, c.z - 1.0f), 0.0f), 15.0f);
        o.z = (cn < 8.0f) ? (1.0f - x.z) : x.z;
    }
    {
        float cn = fminf(fmaxf(fmaf(2.0f, x.w, c.w - 1.0f), 0.0f), 15.0f);
        o.w = (cn < 8.0f) ? (1.0f - x.w) : x.w;
    }

    o4[i] = o;
}

extern "C" void kernel_launch(void* const* d_in, const int* in_sizes, int n_in,
                              void* d_out, int out_size, void* d_ws, size_t ws_size,
                              hipStream_t stream)
{
    const float* x   = (const float*)d_in[0];  // inp_Pr_i_j
    const float* cnt = (const float*)d_in[4];  // cnt_x
    float* out       = (float*)d_out;

    int n  = out_size;          // 16 * 1024 * 1024, divisible by 4
    int n4 = n >> 2;

    const int block = 256;
    int grid = (n4 + block - 1) / block;

    GainesEdgeDetect_kernel<<<grid, block, 0, stream>>>(
        (const float4*)x, (const float4*)cnt, (float4*)out, n4);
}